// Round 1
// baseline (16.392 us; speedup 1.0000x reference)
//
#include <hip/hip_runtime.h>

// Reference reduction (see analysis):
//   nn_idx[0] == 0 always (d2[0,0]=0, exact fp32 int arithmetic, argmin ties -> first index)
//   => exp_neighbor = exp(relu(features[b,0,:]))
//   gamma[i] = max_c( relu(f[i,c]) * exp(relu(f[i,c]) - relu(f[0,c])) ) / max_c relu(f[i,c])
//   out = gamma / ||gamma||_2   (per cloud, concatenated)
// coords (d_in[0]) are dead.

static constexpr int NPTS = 12288;
static constexpr int CCH  = 32;

__global__ void __launch_bounds__(256) gamma_kernel(const float* __restrict__ feats,
                                                    float* __restrict__ out, int N) {
    const int b = blockIdx.y;
    const float* base = feats + (size_t)b * N * CCH;

    // relu(features[b,0,:]) shared by the whole block (L1-resident anyway)
    __shared__ float f0[CCH];
    const int tid = threadIdx.x;
    if (tid < CCH) f0[tid] = fmaxf(base[tid], 0.0f);
    __syncthreads();

    const int i = blockIdx.x * blockDim.x + tid;
    if (i >= N) return;

    const float4* row = reinterpret_cast<const float4*>(base + (size_t)i * CCH);
    float fv[CCH];
    float fm = 0.0f;
#pragma unroll
    for (int q = 0; q < CCH / 4; ++q) {
        float4 v = row[q];
        fv[4 * q + 0] = fmaxf(v.x, 0.0f);
        fv[4 * q + 1] = fmaxf(v.y, 0.0f);
        fv[4 * q + 2] = fmaxf(v.z, 0.0f);
        fv[4 * q + 3] = fmaxf(v.w, 0.0f);
        fm = fmaxf(fm, fmaxf(fmaxf(fv[4 * q + 0], fv[4 * q + 1]),
                             fmaxf(fv[4 * q + 2], fv[4 * q + 3])));
    }

    // gamma = max_c [ f_c * exp(f_c - f0_c) ] / fmax   (all terms >= 0)
    float g = 0.0f;
#pragma unroll
    for (int c = 0; c < CCH; ++c)
        g = fmaxf(g, fv[c] * __expf(fv[c] - f0[c]));

    out[(size_t)b * N + i] = g / fm;
}

// One block per cloud: deterministic block-reduce of sum(gamma^2), then scale in place.
__global__ void __launch_bounds__(1024) norm_kernel(float* __restrict__ out, int N) {
    const int b = blockIdx.x;
    float* g = out + (size_t)b * N;

    __shared__ float red[16];
    float s = 0.0f;
    for (int i = threadIdx.x; i < N; i += blockDim.x) {
        float v = g[i];
        s += v * v;
    }
    // wave-64 reduce
#pragma unroll
    for (int off = 32; off > 0; off >>= 1) s += __shfl_down(s, off);
    const int lane = threadIdx.x & 63;
    const int wv   = threadIdx.x >> 6;
    if (lane == 0) red[wv] = s;
    __syncthreads();
    if (threadIdx.x == 0) {
        float t = 0.0f;
        const int nw = blockDim.x >> 6;
        for (int w = 0; w < nw; ++w) t += red[w];
        red[0] = rsqrtf(t);
    }
    __syncthreads();
    const float scale = red[0];
    for (int i = threadIdx.x; i < N; i += blockDim.x) g[i] *= scale;
}

extern "C" void kernel_launch(void* const* d_in, const int* in_sizes, int n_in,
                              void* d_out, int out_size, void* d_ws, size_t ws_size,
                              hipStream_t stream) {
    const float* feats = (const float*)d_in[1];  // features [B,N,C] float32; coords unused
    float* out = (float*)d_out;                  // [B*N] float32

    const int N = NPTS;
    const int B = out_size / N;

    dim3 grid1((N + 255) / 256, B);
    gamma_kernel<<<grid1, 256, 0, stream>>>(feats, out, N);
    norm_kernel<<<B, 1024, 0, stream>>>(out, N);
}

// Round 2
// 11.810 us; speedup vs baseline: 1.3879x; 1.3879x over previous
//
#include <hip/hip_runtime.h>

// Reference reduction (proven in round 0, absmax 0.0):
//   nn_idx[0] == 0 always  =>  exp_neighbor = exp(relu(features[b,0,:]))
//   gamma[i] = max_c( f_ic * exp(f_ic - f_0c) ) / max_c f_ic,  f = relu(features)
//   out      = gamma / ||gamma||_2 per cloud, concatenated.  coords are dead.
//
// Structure: kernel1 computes gamma + per-block partial sum(gamma^2) -> d_ws;
// kernel2 (96 blocks) sums the 48 partials in fixed order (deterministic),
// then scales its own 256-point chunk. No atomics, no cross-call state.

static constexpr int NPTS = 12288;
static constexpr int CCH  = 32;
static constexpr int BLK  = 256;
static constexpr int NBLK = NPTS / BLK;  // 48 blocks per cloud

__global__ void __launch_bounds__(BLK) gamma_kernel(const float* __restrict__ feats,
                                                    float* __restrict__ out,
                                                    float* __restrict__ partials) {
    const int b = blockIdx.y;
    const float* base = feats + (size_t)b * NPTS * CCH;

    // relu(f[0,:]) — wave-uniform address, compiler scalarizes; L1-resident.
    float f0[CCH];
#pragma unroll
    for (int q = 0; q < CCH / 4; ++q) {
        float4 v = reinterpret_cast<const float4*>(base)[q];
        f0[4 * q + 0] = fmaxf(v.x, 0.0f);
        f0[4 * q + 1] = fmaxf(v.y, 0.0f);
        f0[4 * q + 2] = fmaxf(v.z, 0.0f);
        f0[4 * q + 3] = fmaxf(v.w, 0.0f);
    }

    const int i = blockIdx.x * BLK + threadIdx.x;
    const float4* row = reinterpret_cast<const float4*>(base + (size_t)i * CCH);

    float fm = 0.0f, g = 0.0f;
#pragma unroll
    for (int q = 0; q < CCH / 4; ++q) {
        float4 v = row[q];
        float x0 = fmaxf(v.x, 0.0f), x1 = fmaxf(v.y, 0.0f);
        float x2 = fmaxf(v.z, 0.0f), x3 = fmaxf(v.w, 0.0f);
        fm = fmaxf(fm, fmaxf(fmaxf(x0, x1), fmaxf(x2, x3)));
        g = fmaxf(g, x0 * __expf(x0 - f0[4 * q + 0]));
        g = fmaxf(g, x1 * __expf(x1 - f0[4 * q + 1]));
        g = fmaxf(g, x2 * __expf(x2 - f0[4 * q + 2]));
        g = fmaxf(g, x3 * __expf(x3 - f0[4 * q + 3]));
    }

    const float gamma = g / fm;
    out[(size_t)b * NPTS + i] = gamma;

    // Deterministic block reduction of gamma^2 (fixed shuffle + LDS order).
    float s = gamma * gamma;
#pragma unroll
    for (int off = 32; off > 0; off >>= 1) s += __shfl_down(s, off);
    __shared__ float red[BLK / 64];
    const int lane = threadIdx.x & 63;
    const int wv   = threadIdx.x >> 6;
    if (lane == 0) red[wv] = s;
    __syncthreads();
    if (threadIdx.x == 0)
        partials[b * NBLK + blockIdx.x] = ((red[0] + red[1]) + (red[2] + red[3]));
}

__global__ void __launch_bounds__(BLK) scale_kernel(float* __restrict__ out,
                                                    const float* __restrict__ partials) {
    const int b = blockIdx.y;
    // Fixed-order serial sum of 48 partials: uniform (scalar) loads, deterministic.
    float t = 0.0f;
#pragma unroll
    for (int j = 0; j < NBLK; ++j) t += partials[b * NBLK + j];
    const float sc = rsqrtf(t);

    const int i = blockIdx.x * BLK + threadIdx.x;
    out[(size_t)b * NPTS + i] *= sc;
}

extern "C" void kernel_launch(void* const* d_in, const int* in_sizes, int n_in,
                              void* d_out, int out_size, void* d_ws, size_t ws_size,
                              hipStream_t stream) {
    const float* feats = (const float*)d_in[1];  // features [B,N,C] f32; coords dead
    float* out = (float*)d_out;                  // [B*N] f32
    float* partials = (float*)d_ws;              // [B,48] f32, rewritten every call

    const int B = out_size / NPTS;
    dim3 grid(NBLK, B);
    gamma_kernel<<<grid, BLK, 0, stream>>>(feats, out, partials);
    scale_kernel<<<grid, BLK, 0, stream>>>(out, partials);
}